// Round 1
// 17773.505 us; speedup vs baseline: 1.0188x; 1.0188x over previous
//
#include <hip/hip_runtime.h>
#include <math.h>

// Problem constants (fixed by the reference)
#define NN 100000
#define EE 1600000
// C=64, H=8, D=8

#define SCAN_BS 512
#define NBLK ((NN + SCAN_BS - 1) / SCAN_BS)   // 196

__device__ __forceinline__ float wsum64(float x){
  #pragma unroll
  for (int o = 32; o; o >>= 1) x += __shfl_xor(x, o, 64);
  return x;
}

// ---------------------------------------------------------------------------
// Kernel 1: node pre-norm + q/k projections + fused vni = v * ni.
// One wave per node. (v and ni are only ever consumed as their product in
// the aggregation, so we store the product once: halves the gather traffic.)
// ---------------------------------------------------------------------------
__global__ __launch_bounds__(256) void k_node_pre(
    const float* __restrict__ ns,
    const float* __restrict__ wq, const float* __restrict__ bq,
    const float* __restrict__ wk, const float* __restrict__ bk,
    const float* __restrict__ wv, const float* __restrict__ bv,
    const float* __restrict__ n1g, const float* __restrict__ n1b,
    float* __restrict__ q, float* __restrict__ k, float* __restrict__ vni)
{
  __shared__ float swq[4096], swk[4096], swv[4096];
  for (int i = threadIdx.x; i < 4096; i += 256){ swq[i]=wq[i]; swk[i]=wk[i]; swv[i]=wv[i]; }
  __syncthreads();
  const int wave = threadIdx.x >> 6, lane = threadIdx.x & 63;
  const float gq = bq[lane], gk = bk[lane], gv = bv[lane];
  const float g1 = n1g[lane], b1 = n1b[lane];
  for (int n = blockIdx.x*4 + wave; n < NN; n += gridDim.x*4){
    const float x = ns[(size_t)n*64 + lane];
    const float m = wsum64(x) * (1.f/64.f);
    const float d = x - m;
    const float var = wsum64(d*d) * (1.f/64.f);
    const float niv = d * rsqrtf(var + 1e-5f) * g1 + b1;
    float aq = gq, ak = gk, av = gv;
    #pragma unroll
    for (int i = 0; i < 64; i++){
      const float e_ = __shfl(niv, i, 64);
      aq = fmaf(e_, swq[i*64 + lane], aq);
      ak = fmaf(e_, swk[i*64 + lane], ak);
      av = fmaf(e_, swv[i*64 + lane], av);
    }
    q[(size_t)n*64 + lane]   = aq;
    k[(size_t)n*64 + lane]   = ak;
    vni[(size_t)n*64 + lane] = av * niv;
  }
}

// ---------------------------------------------------------------------------
// CSR build: degree histogram -> hierarchical exclusive scan -> scatter.
// Replaces 102M float scatter-atomics with 3.2M int atomics on small tables.
// ---------------------------------------------------------------------------
__global__ __launch_bounds__(256) void k_deg(const int* __restrict__ eidx,
                                             int* __restrict__ deg)
{
  for (size_t e = (size_t)blockIdx.x*256 + threadIdx.x; e < EE;
       e += (size_t)gridDim.x*256)
    atomicAdd(&deg[eidx[e]], 1);
}

__global__ __launch_bounds__(SCAN_BS) void k_blocksum(const int* __restrict__ deg,
                                                      int* __restrict__ bsum)
{
  __shared__ int sd[SCAN_BS];
  const int i = blockIdx.x*SCAN_BS + threadIdx.x;
  sd[threadIdx.x] = (i < NN) ? deg[i] : 0;
  __syncthreads();
  for (int s = SCAN_BS/2; s; s >>= 1){
    if (threadIdx.x < s) sd[threadIdx.x] += sd[threadIdx.x + s];
    __syncthreads();
  }
  if (threadIdx.x == 0) bsum[blockIdx.x] = sd[0];
}

__global__ __launch_bounds__(256) void k_scan_bsum(const int* __restrict__ bsum,
                                                   int* __restrict__ boff)
{
  __shared__ int s[256];
  const int v = (threadIdx.x < NBLK) ? bsum[threadIdx.x] : 0;
  s[threadIdx.x] = v;
  __syncthreads();
  for (int d = 1; d < 256; d <<= 1){
    const int t = (threadIdx.x >= d) ? s[threadIdx.x - d] : 0;
    __syncthreads();
    s[threadIdx.x] += t;
    __syncthreads();
  }
  if (threadIdx.x < NBLK) boff[threadIdx.x] = s[threadIdx.x] - v;  // exclusive
}

__global__ __launch_bounds__(SCAN_BS) void k_rowstart(const int* __restrict__ deg,
                                                      const int* __restrict__ boff,
                                                      int* __restrict__ rs)
{
  __shared__ int s[SCAN_BS];
  const int i = blockIdx.x*SCAN_BS + threadIdx.x;
  const int v = (i < NN) ? deg[i] : 0;
  s[threadIdx.x] = v;
  __syncthreads();
  for (int d = 1; d < SCAN_BS; d <<= 1){
    const int t = (threadIdx.x >= d) ? s[threadIdx.x - d] : 0;
    __syncthreads();
    s[threadIdx.x] += t;
    __syncthreads();
  }
  if (i < NN) rs[i] = boff[blockIdx.x] + s[threadIdx.x] - v;
}

__global__ __launch_bounds__(256) void k_scatter(const int* __restrict__ eidx,
                                                 const int* __restrict__ rs,
                                                 int* __restrict__ cur,
                                                 int* __restrict__ csr)
{
  for (size_t e = (size_t)blockIdx.x*256 + threadIdx.x; e < EE;
       e += (size_t)gridDim.x*256){
    const int s = eidx[e];
    const int p = atomicAdd(&cur[s], 1);
    csr[rs[s] + p] = (int)e;
  }
}

// ---------------------------------------------------------------------------
// Kernel: edge LN + score projection + exp(score). One wave per edge.
// NO atomics — denominators are computed per-node in k_node_agg.
// exp(s) stored in d_out's attention region (scratch reuse).
// ---------------------------------------------------------------------------
__global__ __launch_bounds__(256) void k_edge1(
    const float* __restrict__ es_in, const int* __restrict__ eidx,
    const float* __restrict__ we, const float* __restrict__ be,
    const float* __restrict__ e1g, const float* __restrict__ e1b,
    const float* __restrict__ q, const float* __restrict__ k,
    float* __restrict__ expo)
{
  __shared__ float swe[4096];
  for (int i = threadIdx.x; i < 4096; i += 256) swe[i] = we[i];
  __syncthreads();
  const int wave = threadIdx.x >> 6, lane = threadIdx.x & 63;
  const float gbe = be[lane], g1 = e1g[lane], b1 = e1b[lane];
  for (size_t e = (size_t)blockIdx.x*4 + wave; e < EE; e += (size_t)gridDim.x*4){
    const float x = es_in[e*64 + lane];
    const float m = wsum64(x) * (1.f/64.f);
    const float d = x - m;
    const float var = wsum64(d*d) * (1.f/64.f);
    const float ei = d * rsqrtf(var + 1e-5f) * g1 + b1;
    float es = gbe;
    #pragma unroll
    for (int i = 0; i < 64; i++){
      es = fmaf(__shfl(ei, i, 64), swe[i*64 + lane], es);
    }
    const int src = eidx[e], dst = eidx[(size_t)EE + e];
    const float qs = q[(size_t)src*64 + lane];
    const float kd = k[(size_t)dst*64 + lane];
    float p = fmaf(qs, kd, es*ei);
    p += __shfl_xor(p, 1, 64); p += __shfl_xor(p, 2, 64); p += __shfl_xor(p, 4, 64);
    const float ev = __expf(p * 0.35355339059327373f); // 1/sqrt(D), D=8
    const float hv = __shfl(ev, (lane & 7)*8, 64);     // all lanes active for shfl
    if (lane < 8) expo[e*8 + lane] = hv;
  }
}

// ---------------------------------------------------------------------------
// Kernel: per-node segment softmax denominator + aggregation + wno matmul
// + residual, all in registers via the CSR. One wave per node, ZERO atomics.
// acc = (sum_e exp_e * vni[dst_e]) / (den + 1e-12) — identical math to
// normalizing each edge first (den is per-head, constant over the segment).
// ---------------------------------------------------------------------------
__global__ __launch_bounds__(256) void k_node_agg(
    const float* __restrict__ ns, const int* __restrict__ eidx,
    const float* __restrict__ vni, const float* __restrict__ expo,
    float* __restrict__ den_out,
    const int* __restrict__ row_start, const int* __restrict__ deg,
    const int* __restrict__ csr,
    const float* __restrict__ wno, const float* __restrict__ bno,
    float* __restrict__ nout)
{
  __shared__ float sw[4096];
  for (int i = threadIdx.x; i < 4096; i += 256) sw[i] = wno[i];
  __syncthreads();
  const int wave = threadIdx.x >> 6, lane = threadIdx.x & 63;
  const int h = lane >> 3;
  const float gb = bno[lane];
  for (int n = blockIdx.x*4 + wave; n < NN; n += gridDim.x*4){
    const int rs = row_start[n], dg = deg[n];
    float den = 0.f, accU = 0.f;
    for (int j0 = 0; j0 < dg; j0 += 64){
      const int rem = dg - j0;
      int eL = 0, dL = 0;
      if (lane < rem){
        eL = csr[rs + j0 + lane];
        dL = eidx[(size_t)EE + eL];
      }
      const int cnt = rem < 64 ? rem : 64;
      for (int j = 0; j < cnt; j++){
        const int e   = __shfl(eL, j, 64);
        const int dst = __shfl(dL, j, 64);
        const float ev = expo[(size_t)e*8 + h];
        den += ev;
        accU = fmaf(ev, vni[(size_t)dst*64 + lane], accU);
      }
    }
    // store per-head denominator (head l's value lives in lanes l*8..l*8+7)
    const float denw = __shfl(den, (lane & 7)*8, 64);
    if (lane < 8) den_out[(size_t)n*8 + lane] = denw;
    const float acc = accU / (den + 1e-12f);
    float o = gb;
    #pragma unroll
    for (int i = 0; i < 64; i++)
      o = fmaf(__shfl(acc, i, 64), sw[i*64 + lane], o);
    nout[(size_t)n*64 + lane] = ns[(size_t)n*64 + lane] + o;
  }
}

// ---------------------------------------------------------------------------
// Kernel: per-edge tail — normalize attention (write final att), edge_update
// @ weo + residual + LN + FFN(64->128->64) + residual. NO atomics.
// One wave per edge, block=512. LDS = 64 KB (ef1w + ef2w).
// ---------------------------------------------------------------------------
__global__ __launch_bounds__(512) void k_edge2(
    const float* __restrict__ es_in, const int* __restrict__ eidx,
    const float* __restrict__ weo, const float* __restrict__ beo,
    const float* __restrict__ e2g, const float* __restrict__ e2b,
    const float* __restrict__ ef1w, const float* __restrict__ ef1b,
    const float* __restrict__ ef2w, const float* __restrict__ ef2b,
    float* __restrict__ att, const float* __restrict__ den,
    float* __restrict__ eout)
{
  __shared__ float sf1[8192];  // ef1w [64,128], 32 KB
  __shared__ float sf2[8192];  // ef2w [128,64], 32 KB
  for (int i = threadIdx.x; i < 8192; i += 512){ sf1[i] = ef1w[i]; sf2[i] = ef2w[i]; }
  __syncthreads();
  const int wave = threadIdx.x >> 6, lane = threadIdx.x & 63;
  const int h = lane >> 3;
  float wo[8];
  #pragma unroll
  for (int hh = 0; hh < 8; hh++) wo[hh] = weo[hh*64 + lane];
  const float gbeo = beo[lane], g2 = e2g[lane], b2 = e2b[lane];
  const float gb1a = ef1b[lane], gb1b = ef1b[64 + lane], gb2 = ef2b[lane];

  for (size_t e = (size_t)blockIdx.x*8 + wave; e < EE; e += (size_t)gridDim.x*8){
    const int src = eidx[e];
    const float ev = att[e*8 + h];                  // exp(score), from k_edge1
    const float dn = den[(size_t)src*8 + h];
    const float a  = ev / (dn + 1e-12f);            // attention for this lane's head
    const float av_ = __shfl(a, (lane & 7)*8, 64);
    if (lane < 8) att[e*8 + lane] = av_;            // final attention output

    // edge_update = attention @ weo + beo
    float eu = gbeo;
    #pragma unroll
    for (int hh = 0; hh < 8; hh++)
      eu = fmaf(__shfl(a, hh*8, 64), wo[hh], eu);
    const float esv = es_in[e*64 + lane] + eu;      // residual

    // pre-norm
    const float m = wsum64(esv) * (1.f/64.f);
    const float d = esv - m;
    const float var = wsum64(d*d) * (1.f/64.f);
    const float t = d * rsqrtf(var + 1e-5f) * g2 + b2;

    // FFN: 64 -> 128 (relu) -> 64, each lane owns cols {lane, lane+64} of h1
    float h1a = gb1a, h1b = gb1b;
    #pragma unroll
    for (int i = 0; i < 64; i++){
      const float ti = __shfl(t, i, 64);
      h1a = fmaf(ti, sf1[i*128 + lane],      h1a);
      h1b = fmaf(ti, sf1[i*128 + 64 + lane], h1b);
    }
    h1a = fmaxf(h1a, 0.f); h1b = fmaxf(h1b, 0.f);
    float o = gb2;
    #pragma unroll
    for (int j = 0; j < 64; j++){
      o = fmaf(__shfl(h1a, j, 64), sf2[j*64 + lane],        o);
      o = fmaf(__shfl(h1b, j, 64), sf2[(64 + j)*64 + lane], o);
    }
    eout[e*64 + lane] = esv + o;                    // residual
  }
}

// ---------------------------------------------------------------------------
// Kernel: node FFN in-place: x += relu(LN(x)@nf1w + nf1b)@nf2w + nf2b
// ---------------------------------------------------------------------------
__global__ __launch_bounds__(256) void k_node_ffn(
    float* __restrict__ x_inout,
    const float* __restrict__ g, const float* __restrict__ b,
    const float* __restrict__ f1w, const float* __restrict__ f1b,
    const float* __restrict__ f2w, const float* __restrict__ f2b)
{
  __shared__ float sf1[8192], sf2[8192];
  for (int i = threadIdx.x; i < 8192; i += 256){ sf1[i] = f1w[i]; sf2[i] = f2w[i]; }
  __syncthreads();
  const int wave = threadIdx.x >> 6, lane = threadIdx.x & 63;
  const float gg = g[lane], gb = b[lane];
  const float b1a = f1b[lane], b1b = f1b[64 + lane], bb2 = f2b[lane];
  for (int n = blockIdx.x*4 + wave; n < NN; n += gridDim.x*4){
    const float x = x_inout[(size_t)n*64 + lane];
    const float m = wsum64(x) * (1.f/64.f);
    const float d = x - m;
    const float var = wsum64(d*d) * (1.f/64.f);
    const float t = d * rsqrtf(var + 1e-5f) * gg + gb;
    float h1a = b1a, h1b = b1b;
    #pragma unroll
    for (int i = 0; i < 64; i++){
      const float ti = __shfl(t, i, 64);
      h1a = fmaf(ti, sf1[i*128 + lane],      h1a);
      h1b = fmaf(ti, sf1[i*128 + 64 + lane], h1b);
    }
    h1a = fmaxf(h1a, 0.f); h1b = fmaxf(h1b, 0.f);
    float o = bb2;
    #pragma unroll
    for (int j = 0; j < 64; j++){
      o = fmaf(__shfl(h1a, j, 64), sf2[j*64 + lane],        o);
      o = fmaf(__shfl(h1b, j, 64), sf2[(64 + j)*64 + lane], o);
    }
    x_inout[(size_t)n*64 + lane] = x + o;
  }
}

// ---------------------------------------------------------------------------
extern "C" void kernel_launch(void* const* d_in, const int* in_sizes, int n_in,
                              void* d_out, int out_size, void* d_ws, size_t ws_size,
                              hipStream_t stream)
{
  // setup_inputs() dict order
  const float* node_states = (const float*)d_in[0];
  const float* edge_states = (const float*)d_in[1];
  const int*   eidx        = (const int*)  d_in[2];
  const float* wq  = (const float*)d_in[3];  const float* bq  = (const float*)d_in[4];
  const float* wk  = (const float*)d_in[5];  const float* bk  = (const float*)d_in[6];
  const float* wv  = (const float*)d_in[7];  const float* bv  = (const float*)d_in[8];
  const float* we  = (const float*)d_in[9];  const float* be  = (const float*)d_in[10];
  const float* wno = (const float*)d_in[11]; const float* bno = (const float*)d_in[12];
  const float* weo = (const float*)d_in[13]; const float* beo = (const float*)d_in[14];
  const float* n1g = (const float*)d_in[15]; const float* n1b = (const float*)d_in[16];
  const float* e1g = (const float*)d_in[17]; const float* e1b = (const float*)d_in[18];
  const float* n2g = (const float*)d_in[19]; const float* n2b = (const float*)d_in[20];
  const float* e2g = (const float*)d_in[21]; const float* e2b = (const float*)d_in[22];
  const float* nf1w= (const float*)d_in[23]; const float* nf1b= (const float*)d_in[24];
  const float* nf2w= (const float*)d_in[25]; const float* nf2b= (const float*)d_in[26];
  const float* ef1w= (const float*)d_in[27]; const float* ef1b= (const float*)d_in[28];
  const float* ef2w= (const float*)d_in[29]; const float* ef2b= (const float*)d_in[30];

  float* out      = (float*)d_out;
  float* out_node = out;                                    // N*64
  float* out_edge = out + (size_t)NN*64;                    // E*64
  float* out_att  = out + (size_t)NN*64 + (size_t)EE*64;    // E*8 (exp scratch -> att)

  // workspace layout (floats): q | k | vni | den | [ints: deg | cur | rs | bsum | boff | csr]
  float* ws    = (float*)d_ws;
  float* w_q   = ws;
  float* w_k   = ws + (size_t)NN*64;
  float* w_vni = ws + (size_t)NN*64*2;
  float* w_den = ws + (size_t)NN*64*3;
  int*   w_deg  = (int*)(ws + (size_t)NN*64*3 + (size_t)NN*8);
  int*   w_cur  = w_deg + NN;
  int*   w_rs   = w_deg + 2*(size_t)NN;
  int*   w_bsum = w_deg + 3*(size_t)NN;
  int*   w_boff = w_bsum + NBLK;
  int*   w_csr  = w_boff + NBLK;

  // zero the histogram + scatter cursors (adjacent -> one memset)
  hipMemsetAsync(w_deg, 0, 2*(size_t)NN*sizeof(int), stream);

  // node pre-norm + projections (independent of CSR)
  hipLaunchKernelGGL(k_node_pre, dim3(6144), dim3(256), 0, stream,
      node_states, wq, bq, wk, bk, wv, bv, n1g, n1b, w_q, w_k, w_vni);

  // CSR build
  hipLaunchKernelGGL(k_deg,      dim3(1024), dim3(256),     0, stream, eidx, w_deg);
  hipLaunchKernelGGL(k_blocksum, dim3(NBLK), dim3(SCAN_BS), 0, stream, w_deg, w_bsum);
  hipLaunchKernelGGL(k_scan_bsum,dim3(1),    dim3(256),     0, stream, w_bsum, w_boff);
  hipLaunchKernelGGL(k_rowstart, dim3(NBLK), dim3(SCAN_BS), 0, stream, w_deg, w_boff, w_rs);
  hipLaunchKernelGGL(k_scatter,  dim3(1024), dim3(256),     0, stream, eidx, w_rs, w_cur, w_csr);

  // edge scores -> exp (no atomics)
  hipLaunchKernelGGL(k_edge1, dim3(8192), dim3(256), 0, stream,
      edge_states, eidx, we, be, e1g, e1b, w_q, w_k, out_att);

  // per-node: denom + aggregation + wno + residual (no atomics)
  hipLaunchKernelGGL(k_node_agg, dim3(6144), dim3(256), 0, stream,
      node_states, eidx, w_vni, out_att, w_den, w_rs, w_deg, w_csr,
      wno, bno, out_node);

  // per-edge tail: attention normalize + edge FFN
  hipLaunchKernelGGL(k_edge2, dim3(4096), dim3(512), 0, stream,
      edge_states, eidx, weo, beo, e2g, e2b,
      ef1w, ef1b, ef2w, ef2b, out_att, w_den, out_edge);

  // node FFN
  hipLaunchKernelGGL(k_node_ffn, dim3(2048), dim3(256), 0, stream,
      out_node, n2g, n2b, nf1w, nf1b, nf2w, nf2b);
}